// Round 1
// baseline (1348.785 us; speedup 1.0000x reference)
//
#include <hip/hip_runtime.h>

#define NLIT 8192
#define NCLS 16384
#define BATCH 4
#define DD 64
#define CCAP 64
#define LCAP 64

__device__ __forceinline__ float leaky(float x){ return x >= 0.f ? x : 0.01f*x; }

// ---- build sparse lists from dense A [NCLS, NLIT] ----
__global__ __launch_bounds__(256) void extract_k(const float* __restrict__ A,
    int* __restrict__ ccnt, int* __restrict__ clist,
    int* __restrict__ lcnt, int* __restrict__ llist){
  const int total4 = NCLS * (NLIT/4);
  int stride = gridDim.x * blockDim.x;
  for (int i = blockIdx.x*blockDim.x + threadIdx.x; i < total4; i += stride){
    float4 v = ((const float4*)A)[i];
    if (v.x!=0.f || v.y!=0.f || v.z!=0.f || v.w!=0.f){
      int c = i >> 11;              // NLIT/4 = 2048
      int l = (i & 2047) << 2;
      float vv[4] = {v.x, v.y, v.z, v.w};
      #pragma unroll
      for (int j=0;j<4;j++){
        if (vv[j]!=0.f){
          int p = atomicAdd(&ccnt[c],1);
          if (p < CCAP) clist[c*CCAP+p] = l+j;
          int q = atomicAdd(&lcnt[l+j],1);
          if (q < LCAP) llist[(l+j)*LCAP+q] = c;
        }
      }
    }
  }
}

// ---- Lmsg = W_Lmsg @ L_t + b, stored node-major [b, l, d] ----
__global__ __launch_bounds__(256) void lmsg_k(const float* __restrict__ L,
    const float* __restrict__ W, const float* __restrict__ bias, float* __restrict__ LmsgT){
  __shared__ float X[64][65];
  __shared__ float Y[64][65];
  int b  = blockIdx.x >> 7;
  int l0 = (blockIdx.x & 127) << 6;
  int lane = threadIdx.x & 63;
  int wg = __builtin_amdgcn_readfirstlane(threadIdx.x >> 6);
  const float* Lb = L + (size_t)b*DD*NLIT;
  #pragma unroll
  for (int r=0;r<16;r++){
    int i = wg + 4*r;
    X[lane][i] = Lb[(size_t)i*NLIT + l0 + lane];
  }
  __syncthreads();
  float acc[16];
  #pragma unroll
  for (int j=0;j<16;j++) acc[j] = bias[wg*16+j];
  #pragma unroll 4
  for (int i=0;i<64;i++){
    float x = X[lane][i];
    #pragma unroll
    for (int j=0;j<16;j++) acc[j] += W[(wg*16+j)*64+i] * x;
  }
  #pragma unroll
  for (int j=0;j<16;j++) Y[lane][wg*16+j] = acc[j];
  __syncthreads();
  float* out = LmsgT + ((size_t)b*NLIT + l0)*64;
  #pragma unroll
  for (int r=0;r<16;r++){
    int cc = wg + 4*r;
    out[cc*64 + lane] = Y[cc][lane];
  }
}

// ---- clause side: gather M_l, C_t_new = leaky(W_Cu@[C;M]+b), Cmsg = W_Cmsg@C_new+b ----
__global__ __launch_bounds__(256) void clause_k(const float* __restrict__ Ct,
    const float* __restrict__ LmsgT, const int* __restrict__ ccnt, const int* __restrict__ clist,
    const float* __restrict__ W_Cu, const float* __restrict__ b_Cu,
    const float* __restrict__ W_Cmsg, const float* __restrict__ b_Cmsg,
    float* __restrict__ CmsgT, float* __restrict__ Csum, float* __restrict__ outC){
  __shared__ float SA[64][65];
  __shared__ float SB[64][65];
  int b  = blockIdx.x >> 8;
  int c0 = (blockIdx.x & 255) << 6;
  int lane = threadIdx.x & 63;
  int wg = __builtin_amdgcn_readfirstlane(threadIdx.x >> 6);
  const float* Cb = Ct + (size_t)b*DD*NCLS;
  #pragma unroll
  for (int r=0;r<16;r++){
    int i = wg + 4*r;
    SA[lane][i] = Cb[(size_t)i*NCLS + c0 + lane];
  }
  const float* Lm = LmsgT + (size_t)b*NLIT*64;
  for (int t=0;t<16;t++){
    int cc = wg*16 + t;
    int c  = c0 + cc;
    int k  = ccnt[c]; if (k > CCAP) k = CCAP;
    float acc = 0.f;
    for (int j=0;j<k;j++){
      int lit = clist[c*CCAP+j];
      acc += Lm[lit*64 + lane];
    }
    SB[cc][lane] = acc;
  }
  __syncthreads();
  float v[16];
  {
    float acc[16];
    #pragma unroll
    for (int j=0;j<16;j++) acc[j] = b_Cu[wg*16+j];
    #pragma unroll 4
    for (int i=0;i<64;i++){
      float xa = SA[lane][i];
      float xm = SB[lane][i];
      #pragma unroll
      for (int j=0;j<16;j++){
        int o = wg*16+j;
        acc[j] += W_Cu[o*128+i]*xa + W_Cu[o*128+64+i]*xm;
      }
    }
    #pragma unroll
    for (int j=0;j<16;j++) v[j] = leaky(acc[j]);
  }
  float* oC = outC + (size_t)b*DD*NCLS;
  #pragma unroll
  for (int j=0;j<16;j++){
    int o = wg*16+j;
    oC[(size_t)o*NCLS + c0 + lane] = v[j];
    float r = v[j];
    #pragma unroll
    for (int s=32;s>0;s>>=1) r += __shfl_xor(r, s, 64);
    if (lane==0) atomicAdd(&Csum[b*64+o], r);
  }
  __syncthreads();
  #pragma unroll
  for (int j=0;j<16;j++) SB[lane][wg*16+j] = v[j];
  __syncthreads();
  float acc2[16];
  #pragma unroll
  for (int j=0;j<16;j++) acc2[j] = b_Cmsg[wg*16+j];
  #pragma unroll 4
  for (int i=0;i<64;i++){
    float x = SB[lane][i];
    #pragma unroll
    for (int j=0;j<16;j++) acc2[j] += W_Cmsg[(wg*16+j)*64+i]*x;
  }
  #pragma unroll
  for (int j=0;j<16;j++) SA[lane][wg*16+j] = acc2[j];
  __syncthreads();
  float* oM = CmsgT + ((size_t)b*NCLS + c0)*64;
  #pragma unroll
  for (int r=0;r<16;r++){
    int cc = wg + 4*r;
    oM[cc*64 + lane] = SA[cc][lane];
  }
}

// ---- literal side: gather M_c, L_t_new = leaky(W_Lu@[L;M;flip(L)]+b) ----
__global__ __launch_bounds__(256) void literal_k(const float* __restrict__ Lt,
    const float* __restrict__ CmsgT, const int* __restrict__ lcnt, const int* __restrict__ llist,
    const float* __restrict__ W_Lu, const float* __restrict__ b_Lu,
    float* __restrict__ Lsum, float* __restrict__ outL){
  __shared__ float SX[64][65];
  __shared__ float SF[64][65];
  __shared__ float SM[64][65];
  int b  = blockIdx.x >> 7;
  int l0 = (blockIdx.x & 127) << 6;
  int lane = threadIdx.x & 63;
  int wg = __builtin_amdgcn_readfirstlane(threadIdx.x >> 6);
  const float* Lb = Lt + (size_t)b*DD*NLIT;
  int f0 = l0 ^ 4096;   // (l + NLIT/2) % NLIT for a 64-aligned tile
  #pragma unroll
  for (int r=0;r<16;r++){
    int i = wg + 4*r;
    SX[lane][i] = Lb[(size_t)i*NLIT + l0 + lane];
    SF[lane][i] = Lb[(size_t)i*NLIT + f0 + lane];
  }
  const float* Cm = CmsgT + (size_t)b*NCLS*64;
  for (int t=0;t<16;t++){
    int cc = wg*16 + t;
    int l  = l0 + cc;
    int k  = lcnt[l]; if (k > LCAP) k = LCAP;
    float acc = 0.f;
    for (int j=0;j<k;j++){
      int c = llist[l*LCAP+j];
      acc += Cm[(size_t)c*64 + lane];
    }
    SM[cc][lane] = acc;
  }
  __syncthreads();
  float acc[16];
  #pragma unroll
  for (int j=0;j<16;j++) acc[j] = b_Lu[wg*16+j];
  #pragma unroll 4
  for (int i=0;i<64;i++){
    float xx = SX[lane][i], xm = SM[lane][i], xf = SF[lane][i];
    #pragma unroll
    for (int j=0;j<16;j++){
      int o = wg*16+j;
      acc[j] += W_Lu[o*192+i]*xx + W_Lu[o*192+64+i]*xm + W_Lu[o*192+128+i]*xf;
    }
  }
  float* oL = outL + (size_t)b*DD*NLIT;
  #pragma unroll
  for (int j=0;j<16;j++){
    int o = wg*16+j;
    float vv = leaky(acc[j]);
    oL[(size_t)o*NLIT + l0 + lane] = vv;
    float r = vv;
    #pragma unroll
    for (int s=32;s>0;s>>=1) r += __shfl_xor(r, s, 64);
    if (lane==0) atomicAdd(&Lsum[b*64+o], r);
  }
}

// ---- global update ----
__global__ void u_k(const float* __restrict__ Lsum, const float* __restrict__ Csum,
                    const float* __restrict__ Ut, const float* __restrict__ W,
                    const float* __restrict__ bias, float* __restrict__ outU){
  int t = threadIdx.x;
  int b = t >> 6, o = t & 63;
  float acc = bias[o];
  for (int i=0;i<64;i++){
    acc += W[o*192+i]*Lsum[b*64+i] + W[o*192+64+i]*Csum[b*64+i] + W[o*192+128+i]*Ut[b*64+i];
  }
  outU[t] = leaky(acc);
}

extern "C" void kernel_launch(void* const* d_in, const int* in_sizes, int n_in,
                              void* d_out, int out_size, void* d_ws, size_t ws_size,
                              hipStream_t stream){
  (void)in_sizes; (void)n_in; (void)out_size; (void)ws_size;
  const float* L_t    = (const float*)d_in[0];
  const float* C_t    = (const float*)d_in[1];
  const float* U_t    = (const float*)d_in[2];
  const float* A      = (const float*)d_in[3];
  // d_in[4] = A_t (unused; A alone gives both orientations)
  const float* W_Lmsg = (const float*)d_in[5];
  const float* b_Lmsg = (const float*)d_in[6];
  const float* W_Cmsg = (const float*)d_in[7];
  const float* b_Cmsg = (const float*)d_in[8];
  const float* W_Lu   = (const float*)d_in[9];
  const float* b_Lu   = (const float*)d_in[10];
  const float* W_Cu   = (const float*)d_in[11];
  const float* b_Cu   = (const float*)d_in[12];
  const float* W_Uu   = (const float*)d_in[13];
  const float* b_Uu   = (const float*)d_in[14];

  char* ws = (char*)d_ws;
  float* LmsgT = (float*)ws;                         // 4*8192*64*4   = 8 MB
  float* CmsgT = (float*)(ws + 8388608);             // 4*16384*64*4  = 16 MB
  int*   ccnt  = (int*)  (ws + 25165824);            // NCLS ints
  int*   lcnt  = (int*)  (ws + 25231360);            // NLIT ints
  float* Lsum  = (float*)(ws + 25264128);            // 256 f
  float* Csum  = (float*)(ws + 25265152);            // 256 f
  int*   clist = (int*)  (ws + 25266176);            // NCLS*CCAP ints = 4 MB
  int*   llist = (int*)  (ws + 29460480);            // NLIT*LCAP ints = 2 MB

  hipMemsetAsync(ws + 25165824, 0, 100352, stream);  // cnts + sums

  float* outL = (float*)d_out;                       // [4,64,8192]
  float* outC = (float*)d_out + 2097152;             // [4,64,16384]
  float* outU = (float*)d_out + 6291456;             // [4,64,1]

  extract_k<<<16384, 256, 0, stream>>>(A, ccnt, clist, lcnt, llist);
  lmsg_k   <<<512,   256, 0, stream>>>(L_t, W_Lmsg, b_Lmsg, LmsgT);
  clause_k <<<1024,  256, 0, stream>>>(C_t, LmsgT, ccnt, clist, W_Cu, b_Cu,
                                       W_Cmsg, b_Cmsg, CmsgT, Csum, outC);
  literal_k<<<512,   256, 0, stream>>>(L_t, CmsgT, lcnt, llist, W_Lu, b_Lu, Lsum, outL);
  u_k      <<<1,     256, 0, stream>>>(Lsum, Csum, U_t, W_Uu, b_Uu, outU);
}

// Round 2
// 1161.637 us; speedup vs baseline: 1.1611x; 1.1611x over previous
//
#include <hip/hip_runtime.h>

#define NLIT 8192
#define NCLS 16384
#define BATCH 4
#define DD 64
#define CCAP 64
#define LCAP 64

__device__ __forceinline__ float leaky(float x){ return x >= 0.f ? x : 0.01f*x; }

// ---- build sparse lists from dense A [NCLS, NLIT] ----
__global__ __launch_bounds__(256) void extract_k(const float* __restrict__ A,
    int* __restrict__ ccnt, int* __restrict__ clist,
    int* __restrict__ lcnt, int* __restrict__ llist){
  const int total4 = NCLS * (NLIT/4);
  int stride = gridDim.x * blockDim.x;
  for (int i = blockIdx.x*blockDim.x + threadIdx.x; i < total4; i += stride){
    float4 v = ((const float4*)A)[i];
    if (v.x!=0.f || v.y!=0.f || v.z!=0.f || v.w!=0.f){
      int c = i >> 11;              // NLIT/4 = 2048
      int l = (i & 2047) << 2;
      float vv[4] = {v.x, v.y, v.z, v.w};
      #pragma unroll
      for (int j=0;j<4;j++){
        if (vv[j]!=0.f){
          int p = atomicAdd(&ccnt[c],1);
          if (p < CCAP) clist[c*CCAP+p] = l+j;
          int q = atomicAdd(&lcnt[l+j],1);
          if (q < LCAP) llist[(l+j)*LCAP+q] = c;
        }
      }
    }
  }
}

// ---- Lmsg = W_Lmsg @ L_t + b, stored node-major [b, l, d] ----
__global__ __launch_bounds__(256) void lmsg_k(const float* __restrict__ L,
    const float* __restrict__ W, const float* __restrict__ bias, float* __restrict__ LmsgT){
  __shared__ float X[64][65];
  __shared__ float Y[64][65];
  int b  = blockIdx.x >> 7;
  int l0 = (blockIdx.x & 127) << 6;
  int lane = threadIdx.x & 63;
  int wg = __builtin_amdgcn_readfirstlane(threadIdx.x >> 6);
  const float* Lb = L + (size_t)b*DD*NLIT;
  #pragma unroll
  for (int r=0;r<16;r++){
    int i = wg + 4*r;
    X[lane][i] = Lb[(size_t)i*NLIT + l0 + lane];
  }
  __syncthreads();
  float acc[16];
  #pragma unroll
  for (int j=0;j<16;j++) acc[j] = bias[wg*16+j];
  #pragma unroll 4
  for (int i=0;i<64;i++){
    float x = X[lane][i];
    #pragma unroll
    for (int j=0;j<16;j++) acc[j] += W[(wg*16+j)*64+i] * x;
  }
  #pragma unroll
  for (int j=0;j<16;j++) Y[lane][wg*16+j] = acc[j];
  __syncthreads();
  float* out = LmsgT + ((size_t)b*NLIT + l0)*64;
  #pragma unroll
  for (int r=0;r<16;r++){
    int cc = wg + 4*r;
    out[cc*64 + lane] = Y[cc][lane];
  }
}

// ---- clause side: gather M_l, C_t_new = leaky(W_Cu@[C;M]+b), Cmsg = W_Cmsg@C_new+b ----
__global__ __launch_bounds__(256) void clause_k(const float* __restrict__ Ct,
    const float* __restrict__ LmsgT, const int* __restrict__ ccnt, const int* __restrict__ clist,
    const float* __restrict__ W_Cu, const float* __restrict__ b_Cu,
    const float* __restrict__ W_Cmsg, const float* __restrict__ b_Cmsg,
    float* __restrict__ CmsgT, float* __restrict__ outC){
  __shared__ float SA[64][65];
  __shared__ float SB[64][65];
  int b  = blockIdx.x >> 8;
  int c0 = (blockIdx.x & 255) << 6;
  int lane = threadIdx.x & 63;
  int wg = __builtin_amdgcn_readfirstlane(threadIdx.x >> 6);
  const float* Cb = Ct + (size_t)b*DD*NCLS;
  #pragma unroll
  for (int r=0;r<16;r++){
    int i = wg + 4*r;
    SA[lane][i] = Cb[(size_t)i*NCLS + c0 + lane];
  }
  const float* Lm = LmsgT + (size_t)b*NLIT*64;
  for (int t=0;t<16;t++){
    int cc = wg*16 + t;
    int c  = c0 + cc;
    int k  = ccnt[c]; if (k > CCAP) k = CCAP;
    float acc = 0.f;
    for (int j=0;j<k;j++){
      int lit = clist[c*CCAP+j];
      acc += Lm[lit*64 + lane];
    }
    SB[cc][lane] = acc;
  }
  __syncthreads();
  float v[16];
  {
    float acc[16];
    #pragma unroll
    for (int j=0;j<16;j++) acc[j] = b_Cu[wg*16+j];
    #pragma unroll 4
    for (int i=0;i<64;i++){
      float xa = SA[lane][i];
      float xm = SB[lane][i];
      #pragma unroll
      for (int j=0;j<16;j++){
        int o = wg*16+j;
        acc[j] += W_Cu[o*128+i]*xa + W_Cu[o*128+64+i]*xm;
      }
    }
    #pragma unroll
    for (int j=0;j<16;j++) v[j] = leaky(acc[j]);
  }
  float* oC = outC + (size_t)b*DD*NCLS;
  #pragma unroll
  for (int j=0;j<16;j++){
    int o = wg*16+j;
    oC[(size_t)o*NCLS + c0 + lane] = v[j];
  }
  __syncthreads();
  #pragma unroll
  for (int j=0;j<16;j++) SB[lane][wg*16+j] = v[j];
  __syncthreads();
  float acc2[16];
  #pragma unroll
  for (int j=0;j<16;j++) acc2[j] = b_Cmsg[wg*16+j];
  #pragma unroll 4
  for (int i=0;i<64;i++){
    float x = SB[lane][i];
    #pragma unroll
    for (int j=0;j<16;j++) acc2[j] += W_Cmsg[(wg*16+j)*64+i]*x;
  }
  #pragma unroll
  for (int j=0;j<16;j++) SA[lane][wg*16+j] = acc2[j];
  __syncthreads();
  float* oM = CmsgT + ((size_t)b*NCLS + c0)*64;
  #pragma unroll
  for (int r=0;r<16;r++){
    int cc = wg + 4*r;
    oM[cc*64 + lane] = SA[cc][lane];
  }
}

// ---- literal side: gather M_c, L_t_new = leaky(W_Lu@[L;M;flip(L)]+b) ----
__global__ __launch_bounds__(256) void literal_k(const float* __restrict__ Lt,
    const float* __restrict__ CmsgT, const int* __restrict__ lcnt, const int* __restrict__ llist,
    const float* __restrict__ W_Lu, const float* __restrict__ b_Lu,
    float* __restrict__ outL){
  __shared__ float SX[64][65];
  __shared__ float SF[64][65];
  __shared__ float SM[64][65];
  int b  = blockIdx.x >> 7;
  int l0 = (blockIdx.x & 127) << 6;
  int lane = threadIdx.x & 63;
  int wg = __builtin_amdgcn_readfirstlane(threadIdx.x >> 6);
  const float* Lb = Lt + (size_t)b*DD*NLIT;
  int f0 = l0 ^ 4096;   // (l + NLIT/2) % NLIT for a 64-aligned tile
  #pragma unroll
  for (int r=0;r<16;r++){
    int i = wg + 4*r;
    SX[lane][i] = Lb[(size_t)i*NLIT + l0 + lane];
    SF[lane][i] = Lb[(size_t)i*NLIT + f0 + lane];
  }
  const float* Cm = CmsgT + (size_t)b*NCLS*64;
  for (int t=0;t<16;t++){
    int cc = wg*16 + t;
    int l  = l0 + cc;
    int k  = lcnt[l]; if (k > LCAP) k = LCAP;
    float acc = 0.f;
    for (int j=0;j<k;j++){
      int c = llist[l*LCAP+j];
      acc += Cm[(size_t)c*64 + lane];
    }
    SM[cc][lane] = acc;
  }
  __syncthreads();
  float acc[16];
  #pragma unroll
  for (int j=0;j<16;j++) acc[j] = b_Lu[wg*16+j];
  #pragma unroll 4
  for (int i=0;i<64;i++){
    float xx = SX[lane][i], xm = SM[lane][i], xf = SF[lane][i];
    #pragma unroll
    for (int j=0;j<16;j++){
      int o = wg*16+j;
      acc[j] += W_Lu[o*192+i]*xx + W_Lu[o*192+64+i]*xm + W_Lu[o*192+128+i]*xf;
    }
  }
  float* oL = outL + (size_t)b*DD*NLIT;
  #pragma unroll
  for (int j=0;j<16;j++){
    int o = wg*16+j;
    oL[(size_t)o*NLIT + l0 + lane] = leaky(acc[j]);
  }
}

// ---- row sums of outL/outC (replaces contended atomics) ----
// blocks [0,256): Csum rows; blocks [256,512): Lsum rows
__global__ __launch_bounds__(256) void reduce_k(const float* __restrict__ outL,
    const float* __restrict__ outC, float* __restrict__ Lsum, float* __restrict__ Csum){
  __shared__ float red[256];
  int r = blockIdx.x;
  int t = threadIdx.x;
  float s = 0.f;
  if (r < 256){
    const float4* p = (const float4*)(outC + (size_t)r*NCLS);
    #pragma unroll
    for (int i=0;i<16;i++){
      float4 v = p[t + 256*i];
      s += v.x + v.y + v.z + v.w;
    }
  } else {
    const float4* p = (const float4*)(outL + (size_t)(r-256)*NLIT);
    #pragma unroll
    for (int i=0;i<8;i++){
      float4 v = p[t + 256*i];
      s += v.x + v.y + v.z + v.w;
    }
  }
  #pragma unroll
  for (int sft=32;sft>0;sft>>=1) s += __shfl_xor(s, sft, 64);
  if ((t & 63) == 0) red[t >> 6] = s;
  __syncthreads();
  if (t == 0){
    float tot = red[0] + red[1] + red[2] + red[3];
    if (r < 256) Csum[r] = tot; else Lsum[r-256] = tot;
  }
}

// ---- global update ----
__global__ void u_k(const float* __restrict__ Lsum, const float* __restrict__ Csum,
                    const float* __restrict__ Ut, const float* __restrict__ W,
                    const float* __restrict__ bias, float* __restrict__ outU){
  int t = threadIdx.x;
  int b = t >> 6, o = t & 63;
  float acc = bias[o];
  for (int i=0;i<64;i++){
    acc += W[o*192+i]*Lsum[b*64+i] + W[o*192+64+i]*Csum[b*64+i] + W[o*192+128+i]*Ut[b*64+i];
  }
  outU[t] = leaky(acc);
}

extern "C" void kernel_launch(void* const* d_in, const int* in_sizes, int n_in,
                              void* d_out, int out_size, void* d_ws, size_t ws_size,
                              hipStream_t stream){
  (void)in_sizes; (void)n_in; (void)out_size; (void)ws_size;
  const float* L_t    = (const float*)d_in[0];
  const float* C_t    = (const float*)d_in[1];
  const float* U_t    = (const float*)d_in[2];
  const float* A      = (const float*)d_in[3];
  // d_in[4] = A_t (unused; A alone gives both orientations)
  const float* W_Lmsg = (const float*)d_in[5];
  const float* b_Lmsg = (const float*)d_in[6];
  const float* W_Cmsg = (const float*)d_in[7];
  const float* b_Cmsg = (const float*)d_in[8];
  const float* W_Lu   = (const float*)d_in[9];
  const float* b_Lu   = (const float*)d_in[10];
  const float* W_Cu   = (const float*)d_in[11];
  const float* b_Cu   = (const float*)d_in[12];
  const float* W_Uu   = (const float*)d_in[13];
  const float* b_Uu   = (const float*)d_in[14];

  char* ws = (char*)d_ws;
  float* LmsgT = (float*)ws;                         // 4*8192*64*4   = 8 MB
  float* CmsgT = (float*)(ws + 8388608);             // 4*16384*64*4  = 16 MB
  int*   ccnt  = (int*)  (ws + 25165824);            // NCLS ints (64 KB)
  int*   lcnt  = (int*)  (ws + 25231360);            // NLIT ints (32 KB)
  float* Lsum  = (float*)(ws + 25264128);            // 256 f
  float* Csum  = (float*)(ws + 25265152);            // 256 f
  int*   clist = (int*)  (ws + 25266176);            // NCLS*CCAP ints = 4 MB
  int*   llist = (int*)  (ws + 29460480);            // NLIT*LCAP ints = 2 MB

  hipMemsetAsync(ws + 25165824, 0, 98304, stream);   // ccnt + lcnt only

  float* outL = (float*)d_out;                       // [4,64,8192]
  float* outC = (float*)d_out + 2097152;             // [4,64,16384]
  float* outU = (float*)d_out + 6291456;             // [4,64,1]

  extract_k<<<16384, 256, 0, stream>>>(A, ccnt, clist, lcnt, llist);
  lmsg_k   <<<512,   256, 0, stream>>>(L_t, W_Lmsg, b_Lmsg, LmsgT);
  clause_k <<<1024,  256, 0, stream>>>(C_t, LmsgT, ccnt, clist, W_Cu, b_Cu,
                                       W_Cmsg, b_Cmsg, CmsgT, outC);
  literal_k<<<512,   256, 0, stream>>>(L_t, CmsgT, lcnt, llist, W_Lu, b_Lu, outL);
  reduce_k <<<512,   256, 0, stream>>>(outL, outC, Lsum, Csum);
  u_k      <<<1,     256, 0, stream>>>(Lsum, Csum, U_t, W_Uu, b_Uu, outU);
}

// Round 3
// 1098.602 us; speedup vs baseline: 1.2277x; 1.0574x over previous
//
#include <hip/hip_runtime.h>

#define NLIT 8192
#define NCLS 16384
#define BATCH 4
#define DD 64
#define CCAP 64
#define LCAP 64

__device__ __forceinline__ float leaky(float x){ return x >= 0.f ? x : 0.01f*x; }

// ---- build sparse lists from dense A [NCLS, NLIT] ----
__global__ __launch_bounds__(256) void extract_k(const float* __restrict__ A,
    int* __restrict__ ccnt, int* __restrict__ clist,
    int* __restrict__ lcnt, int* __restrict__ llist){
  const int total4 = NCLS * (NLIT/4);
  int stride = gridDim.x * blockDim.x;
  for (int i = blockIdx.x*blockDim.x + threadIdx.x; i < total4; i += stride){
    float4 v = ((const float4*)A)[i];
    if (v.x!=0.f || v.y!=0.f || v.z!=0.f || v.w!=0.f){
      int c = i >> 11;              // NLIT/4 = 2048
      int l = (i & 2047) << 2;
      float vv[4] = {v.x, v.y, v.z, v.w};
      #pragma unroll
      for (int j=0;j<4;j++){
        if (vv[j]!=0.f){
          int p = atomicAdd(&ccnt[c],1);
          if (p < CCAP) clist[c*CCAP+p] = l+j;
          int q = atomicAdd(&lcnt[l+j],1);
          if (q < LCAP) llist[(l+j)*LCAP+q] = c;
        }
      }
    }
  }
}

// ---- Lmsg = W_Lmsg @ L_t + b, stored node-major [b, l, d] ----
__global__ __launch_bounds__(256) void lmsg_k(const float* __restrict__ L,
    const float* __restrict__ W, const float* __restrict__ bias, float* __restrict__ LmsgT){
  __shared__ float X[64][65];
  __shared__ float Y[64][65];
  int b  = blockIdx.x >> 7;
  int l0 = (blockIdx.x & 127) << 6;
  int lane = threadIdx.x & 63;
  int wg = __builtin_amdgcn_readfirstlane(threadIdx.x >> 6);
  const float* Lb = L + (size_t)b*DD*NLIT;
  #pragma unroll
  for (int r=0;r<16;r++){
    int i = wg + 4*r;
    X[lane][i] = Lb[(size_t)i*NLIT + l0 + lane];
  }
  __syncthreads();
  float acc[16];
  #pragma unroll
  for (int j=0;j<16;j++) acc[j] = bias[wg*16+j];
  #pragma unroll 4
  for (int i=0;i<64;i++){
    float x = X[lane][i];
    #pragma unroll
    for (int j=0;j<16;j++) acc[j] += W[(wg*16+j)*64+i] * x;
  }
  #pragma unroll
  for (int j=0;j<16;j++) Y[lane][wg*16+j] = acc[j];
  __syncthreads();
  float* out = LmsgT + ((size_t)b*NLIT + l0)*64;
  #pragma unroll
  for (int r=0;r<16;r++){
    int cc = wg + 4*r;
    out[cc*64 + lane] = Y[cc][lane];
  }
}

// de-chained gather of one node's neighbor sum: indices loaded int4-wide,
// 4 independent 256B line gathers in flight per index load
__device__ __forceinline__ float gather_sum(const float* __restrict__ src,
    const int* __restrict__ list, int k, int lane){
  float acc = 0.f;
  int j = 0;
  for (; j+4 <= k; j += 4){
    int4 li = *(const int4*)&list[j];
    float a0 = src[(size_t)li.x*64 + lane];
    float a1 = src[(size_t)li.y*64 + lane];
    float a2 = src[(size_t)li.z*64 + lane];
    float a3 = src[(size_t)li.w*64 + lane];
    acc += (a0 + a1) + (a2 + a3);
  }
  for (; j < k; j++) acc += src[(size_t)list[j]*64 + lane];
  return acc;
}

// ---- clause side: gather M_l, C_t_new = leaky(W_Cu@[C;M]+b), Cmsg = W_Cmsg@C_new+b ----
__global__ __launch_bounds__(256) void clause_k(const float* __restrict__ Ct,
    const float* __restrict__ LmsgT, const int* __restrict__ ccnt, const int* __restrict__ clist,
    const float* __restrict__ W_Cu, const float* __restrict__ b_Cu,
    const float* __restrict__ W_Cmsg, const float* __restrict__ b_Cmsg,
    float* __restrict__ CmsgT, float* __restrict__ outC){
  __shared__ float SA[64][65];
  __shared__ float SB[64][65];
  int b  = blockIdx.x >> 8;
  int c0 = (blockIdx.x & 255) << 6;
  int lane = threadIdx.x & 63;
  int wg = __builtin_amdgcn_readfirstlane(threadIdx.x >> 6);
  // hoist counts: 16 independent loads up front
  int kk[16];
  #pragma unroll
  for (int t=0;t<16;t++){
    int k = ccnt[c0 + wg*16 + t];
    kk[t] = k > CCAP ? CCAP : k;
  }
  const float* Cb = Ct + (size_t)b*DD*NCLS;
  #pragma unroll
  for (int r=0;r<16;r++){
    int i = wg + 4*r;
    SA[lane][i] = Cb[(size_t)i*NCLS + c0 + lane];
  }
  const float* Lm = LmsgT + (size_t)b*NLIT*64;
  #pragma unroll 2
  for (int t=0;t<16;t++){
    int cc = wg*16 + t;
    int c  = c0 + cc;
    SB[cc][lane] = gather_sum(Lm, &clist[c*CCAP], kk[t], lane);
  }
  __syncthreads();
  float v[16];
  {
    float acc[16];
    #pragma unroll
    for (int j=0;j<16;j++) acc[j] = b_Cu[wg*16+j];
    #pragma unroll 4
    for (int i=0;i<64;i++){
      float xa = SA[lane][i];
      float xm = SB[lane][i];
      #pragma unroll
      for (int j=0;j<16;j++){
        int o = wg*16+j;
        acc[j] += W_Cu[o*128+i]*xa + W_Cu[o*128+64+i]*xm;
      }
    }
    #pragma unroll
    for (int j=0;j<16;j++) v[j] = leaky(acc[j]);
  }
  float* oC = outC + (size_t)b*DD*NCLS;
  #pragma unroll
  for (int j=0;j<16;j++){
    int o = wg*16+j;
    oC[(size_t)o*NCLS + c0 + lane] = v[j];
  }
  __syncthreads();
  #pragma unroll
  for (int j=0;j<16;j++) SB[lane][wg*16+j] = v[j];
  __syncthreads();
  float acc2[16];
  #pragma unroll
  for (int j=0;j<16;j++) acc2[j] = b_Cmsg[wg*16+j];
  #pragma unroll 4
  for (int i=0;i<64;i++){
    float x = SB[lane][i];
    #pragma unroll
    for (int j=0;j<16;j++) acc2[j] += W_Cmsg[(wg*16+j)*64+i]*x;
  }
  #pragma unroll
  for (int j=0;j<16;j++) SA[lane][wg*16+j] = acc2[j];
  __syncthreads();
  float* oM = CmsgT + ((size_t)b*NCLS + c0)*64;
  #pragma unroll
  for (int r=0;r<16;r++){
    int cc = wg + 4*r;
    oM[cc*64 + lane] = SA[cc][lane];
  }
}

// ---- literal side: gather M_c, L_t_new = leaky(W_Lu@[L;M;flip(L)]+b) ----
__global__ __launch_bounds__(256) void literal_k(const float* __restrict__ Lt,
    const float* __restrict__ CmsgT, const int* __restrict__ lcnt, const int* __restrict__ llist,
    const float* __restrict__ W_Lu, const float* __restrict__ b_Lu,
    float* __restrict__ outL){
  __shared__ float SX[64][65];
  __shared__ float SF[64][65];
  __shared__ float SM[64][65];
  int b  = blockIdx.x >> 7;
  int l0 = (blockIdx.x & 127) << 6;
  int lane = threadIdx.x & 63;
  int wg = __builtin_amdgcn_readfirstlane(threadIdx.x >> 6);
  int kk[16];
  #pragma unroll
  for (int t=0;t<16;t++){
    int k = lcnt[l0 + wg*16 + t];
    kk[t] = k > LCAP ? LCAP : k;
  }
  const float* Lb = Lt + (size_t)b*DD*NLIT;
  int f0 = l0 ^ 4096;   // (l + NLIT/2) % NLIT for a 64-aligned tile
  #pragma unroll
  for (int r=0;r<16;r++){
    int i = wg + 4*r;
    SX[lane][i] = Lb[(size_t)i*NLIT + l0 + lane];
    SF[lane][i] = Lb[(size_t)i*NLIT + f0 + lane];
  }
  const float* Cm = CmsgT + (size_t)b*NCLS*64;
  #pragma unroll 2
  for (int t=0;t<16;t++){
    int cc = wg*16 + t;
    int l  = l0 + cc;
    SM[cc][lane] = gather_sum(Cm, &llist[l*LCAP], kk[t], lane);
  }
  __syncthreads();
  float acc[16];
  #pragma unroll
  for (int j=0;j<16;j++) acc[j] = b_Lu[wg*16+j];
  #pragma unroll 4
  for (int i=0;i<64;i++){
    float xx = SX[lane][i], xm = SM[lane][i], xf = SF[lane][i];
    #pragma unroll
    for (int j=0;j<16;j++){
      int o = wg*16+j;
      acc[j] += W_Lu[o*192+i]*xx + W_Lu[o*192+64+i]*xm + W_Lu[o*192+128+i]*xf;
    }
  }
  float* oL = outL + (size_t)b*DD*NLIT;
  #pragma unroll
  for (int j=0;j<16;j++){
    int o = wg*16+j;
    oL[(size_t)o*NLIT + l0 + lane] = leaky(acc[j]);
  }
}

// ---- row sums of outL/outC ----
__global__ __launch_bounds__(256) void reduce_k(const float* __restrict__ outL,
    const float* __restrict__ outC, float* __restrict__ Lsum, float* __restrict__ Csum){
  __shared__ float red[4];
  int r = blockIdx.x;
  int t = threadIdx.x;
  float s = 0.f;
  if (r < 256){
    const float4* p = (const float4*)(outC + (size_t)r*NCLS);
    #pragma unroll
    for (int i=0;i<16;i++){
      float4 v = p[t + 256*i];
      s += v.x + v.y + v.z + v.w;
    }
  } else {
    const float4* p = (const float4*)(outL + (size_t)(r-256)*NLIT);
    #pragma unroll
    for (int i=0;i<8;i++){
      float4 v = p[t + 256*i];
      s += v.x + v.y + v.z + v.w;
    }
  }
  #pragma unroll
  for (int sft=32;sft>0;sft>>=1) s += __shfl_xor(s, sft, 64);
  if ((t & 63) == 0) red[t >> 6] = s;
  __syncthreads();
  if (t == 0){
    float tot = red[0] + red[1] + red[2] + red[3];
    if (r < 256) Csum[r] = tot; else Lsum[r-256] = tot;
  }
}

// ---- global update ----
__global__ void u_k(const float* __restrict__ Lsum, const float* __restrict__ Csum,
                    const float* __restrict__ Ut, const float* __restrict__ W,
                    const float* __restrict__ bias, float* __restrict__ outU){
  int t = threadIdx.x;
  int b = t >> 6, o = t & 63;
  float acc = bias[o];
  for (int i=0;i<64;i++){
    acc += W[o*192+i]*Lsum[b*64+i] + W[o*192+64+i]*Csum[b*64+i] + W[o*192+128+i]*Ut[b*64+i];
  }
  outU[t] = leaky(acc);
}

extern "C" void kernel_launch(void* const* d_in, const int* in_sizes, int n_in,
                              void* d_out, int out_size, void* d_ws, size_t ws_size,
                              hipStream_t stream){
  (void)in_sizes; (void)n_in; (void)out_size; (void)ws_size;
  const float* L_t    = (const float*)d_in[0];
  const float* C_t    = (const float*)d_in[1];
  const float* U_t    = (const float*)d_in[2];
  const float* A      = (const float*)d_in[3];
  // d_in[4] = A_t (unused)
  const float* W_Lmsg = (const float*)d_in[5];
  const float* b_Lmsg = (const float*)d_in[6];
  const float* W_Cmsg = (const float*)d_in[7];
  const float* b_Cmsg = (const float*)d_in[8];
  const float* W_Lu   = (const float*)d_in[9];
  const float* b_Lu   = (const float*)d_in[10];
  const float* W_Cu   = (const float*)d_in[11];
  const float* b_Cu   = (const float*)d_in[12];
  const float* W_Uu   = (const float*)d_in[13];
  const float* b_Uu   = (const float*)d_in[14];

  char* ws = (char*)d_ws;
  float* LmsgT = (float*)ws;                         // 8 MB
  float* CmsgT = (float*)(ws + 8388608);             // 16 MB
  int*   ccnt  = (int*)  (ws + 25165824);            // 64 KB
  int*   lcnt  = (int*)  (ws + 25231360);            // 32 KB
  float* Lsum  = (float*)(ws + 25264128);            // 256 f
  float* Csum  = (float*)(ws + 25265152);            // 256 f
  int*   clist = (int*)  (ws + 25266176);            // 4 MB
  int*   llist = (int*)  (ws + 29460480);            // 2 MB

  hipMemsetAsync(ws + 25165824, 0, 98304, stream);   // ccnt + lcnt

  float* outL = (float*)d_out;                       // [4,64,8192]
  float* outC = (float*)d_out + 2097152;             // [4,64,16384]
  float* outU = (float*)d_out + 6291456;             // [4,64,1]

  extract_k<<<16384, 256, 0, stream>>>(A, ccnt, clist, lcnt, llist);
  lmsg_k   <<<512,   256, 0, stream>>>(L_t, W_Lmsg, b_Lmsg, LmsgT);
  clause_k <<<1024,  256, 0, stream>>>(C_t, LmsgT, ccnt, clist, W_Cu, b_Cu,
                                       W_Cmsg, b_Cmsg, CmsgT, outC);
  literal_k<<<512,   256, 0, stream>>>(L_t, CmsgT, lcnt, llist, W_Lu, b_Lu, outL);
  reduce_k <<<512,   256, 0, stream>>>(outL, outC, Lsum, Csum);
  u_k      <<<1,     256, 0, stream>>>(Lsum, Csum, U_t, W_Uu, b_Uu, outU);
}